// Round 14
// baseline (34.966 us; speedup 1.0000x reference)
//
#include <hip/hip_runtime.h>

typedef unsigned short ushort_t;
using f32x4  = __attribute__((ext_vector_type(4))) float;
using bf16x8 = __attribute__((ext_vector_type(8))) short;
using u16x8  = __attribute__((ext_vector_type(8))) unsigned short;
using h2v    = __attribute__((ext_vector_type(2))) _Float16;
using u32x4  = __attribute__((ext_vector_type(4))) unsigned;

constexpr int Bc = 4;
constexpr int Nc = 512;
constexpr int Dc = 512;
constexpr int Pc = 128;
constexpr int ROWS = Bc * Nc;   // 2048

__device__ inline unsigned short f2bf(float f) {
    unsigned u = __builtin_bit_cast(unsigned, f);
    unsigned r = u + 0x7fffu + ((u >> 16) & 1u);   // RNE
    return (unsigned short)(r >> 16);
}

__device__ inline unsigned packh2(float a, float b) {
    unsigned short lo = __builtin_bit_cast(unsigned short, (_Float16)a);
    unsigned short hi = __builtin_bit_cast(unsigned short, (_Float16)b);
    return (unsigned)lo | ((unsigned)hi << 16);
}

// ---------------------------------------------------------------------------
// K1: proj GEMM, fully fused (input conversion + W conversion in-kernel).
// grid (64 mt2, 8 ny) = 512 blocks, 256 thr, 2 blocks/CU (LDS 72.8 KB).
// A: fp32 input -> bf16 MFMA fragments in REGISTERS (16 frags/lane, proven
//    proj4 lane mapping). B: fp32 W -> bf16 fragments in LDS via 16-step
//    staged transpose (wconv's verified mapping, LDS dest). Main K-loop is
//    barrier-free: 8 x (4 ds_read_b128 + 4 MFMA).
// ny 0..3 -> leftH/rightH (f16); ny 4..7 -> start/end partials -> parts.
// ---------------------------------------------------------------------------
__global__ __launch_bounds__(256, 2) void mfma_proj5(
    const float* __restrict__ input,
    const float* __restrict__ Wl,  const float* __restrict__ bl,
    const float* __restrict__ Wr,
    const float* __restrict__ Ws1, const float* __restrict__ bs1,
    const float* __restrict__ Ws2,
    const float* __restrict__ We1, const float* __restrict__ be1,
    const float* __restrict__ We2,
    ushort_t* __restrict__ leftH, ushort_t* __restrict__ rightH,
    float* __restrict__ parts)
{
    const int mt2 = blockIdx.x, ny = blockIdx.y;
    const int row0 = mt2 * 32;
    const int t = threadIdx.x, w = t >> 6, l = t & 63;
    const int wm = w & 1, wn = w >> 1;
    const int fr = l & 15, fg = l >> 4;

    __shared__ ushort_t Bs[8 * 4096];   // 64 KB: [ks(8)][kc(8)][col(64)][8]
    __shared__ float Tst[32][68];       // 8.5 KB staging for W transpose
    __shared__ float red[64];

    // ---- A: fp32 -> bf16 fragments in registers (proven proj4 mapping:
    //      afrag[ks][kk] = input[row0+wm*16+fr][ks*64 + (kk*4+fg)*8 .. +8])
    const float* Ain = input + (size_t)(row0 + wm * 16 + fr) * Dc + fg * 8;
    bf16x8 afrag[8][2];
    #pragma unroll
    for (int ks = 0; ks < 8; ++ks) {
        #pragma unroll
        for (int kk = 0; kk < 2; ++kk) {
            const float* s = Ain + ks * 64 + kk * 32;
            float4 v0 = *(const float4*)s;
            float4 v1 = *(const float4*)(s + 4);
            u16x8 o;
            o[0] = f2bf(v0.x); o[1] = f2bf(v0.y); o[2] = f2bf(v0.z); o[3] = f2bf(v0.w);
            o[4] = f2bf(v1.x); o[5] = f2bf(v1.y); o[6] = f2bf(v1.z); o[7] = f2bf(v1.w);
            afrag[ks][kk] = __builtin_bit_cast(bf16x8, o);
        }
    }

    // ---- B: fp32 W -> bf16 fragments in LDS (wconv's verified transpose,
    //      16 iterations of 32 k-rows; fragment k = h*32 + kcl*8 + i) ----
    const int mi = ny >> 1, cm0 = (ny & 1) * 64;
    const float* Wm = (mi == 0) ? Wl : (mi == 1) ? Wr : (mi == 2) ? Ws1 : We1;
    const int kcl = t >> 6, col = t & 63;

    #pragma unroll 1
    for (int h = 0; h < 16; ++h) {
        #pragma unroll
        for (int u = 0; u < 2; ++u) {
            int idx = t + u * 256, kr = idx >> 4, c4 = (idx & 15) * 4;
            *(float4*)&Tst[kr][c4] =
                *(const float4*)&Wm[(size_t)(h * 32 + kr) * Pc + cm0 + c4];
        }
        __syncthreads();
        u16x8 o;
        #pragma unroll
        for (int i = 0; i < 8; ++i) o[i] = f2bf(Tst[kcl * 8 + i][col]);
        const int ks = h >> 1, kc = (h & 1) * 4 + kcl;
        *(u16x8*)&Bs[ks * 4096 + kc * 512 + col * 8] = o;
        __syncthreads();
    }

    // ---- main loop: barrier-free ----
    f32x4 acc0 = {0.f, 0.f, 0.f, 0.f}, acc1 = {0.f, 0.f, 0.f, 0.f};
    #pragma unroll
    for (int ks = 0; ks < 8; ++ks) {
        #pragma unroll
        for (int kk = 0; kk < 2; ++kk) {
            const int kc = kk * 4 + fg;
            bf16x8 b0 = *(const bf16x8*)&Bs[ks * 4096 + kc * 512 + (wn * 32 + fr) * 8];
            bf16x8 b1 = *(const bf16x8*)&Bs[ks * 4096 + kc * 512 + (wn * 32 + 16 + fr) * 8];
            acc0 = __builtin_amdgcn_mfma_f32_16x16x32_bf16(afrag[ks][kk], b0, acc0, 0, 0, 0);
            acc1 = __builtin_amdgcn_mfma_f32_16x16x32_bf16(afrag[ks][kk], b1, acc1, 0, 0, 0);
        }
    }

    // ---- epilogue (byte-identical to proj4) ----
    const int fq4 = fg << 2;
    if (ny < 4) {
        ushort_t* outp = (ny < 2) ? leftH : rightH;
        const int cb = (ny & 1) * 64 + wn * 32;
        #pragma unroll
        for (int n = 0; n < 2; ++n) {
            const int colo = cb + n * 16 + fr;
            const float bv = (ny < 2) ? bl[colo] : 0.f;
            const f32x4 av = n ? acc1 : acc0;
            #pragma unroll
            for (int q = 0; q < 4; ++q) {
                float v = av[q] + bv;
                leftH[0] = leftH[0];  // no-op guard removed below
                outp[(size_t)(row0 + wm * 16 + fq4 + q) * Pc + colo] =
                    __builtin_bit_cast(ushort_t, (_Float16)v);
            }
        }
    } else {
        const int pi = ny - 4;
        const float* b1 = (ny < 6) ? bs1 : be1;
        const float* W2 = (ny < 6) ? Ws2 : We2;
        const int pb = (pi & 1) * 64;
        #pragma unroll
        for (int q = 0; q < 4; ++q) {
            const int cp0 = pb + wn * 32 + fr;
            const int cp1 = pb + wn * 32 + 16 + fr;
            float v = fmaxf(acc0[q] + b1[cp0], 0.f) * W2[cp0]
                    + fmaxf(acc1[q] + b1[cp1], 0.f) * W2[cp1];
            v += __shfl_xor(v, 1);
            v += __shfl_xor(v, 2);
            v += __shfl_xor(v, 4);
            v += __shfl_xor(v, 8);
            if (fr == 0) red[wn * 32 + wm * 16 + fq4 + q] = v;
        }
        __syncthreads();
        if (t < 32) parts[pi * ROWS + row0 + t] = red[t] + red[32 + t];
    }
}

// ---------------------------------------------------------------------------
// K2: bigram v9 (unchanged) — no-LDS, no-barrier, 1-wave blocks.
// grid (128, 9, 4), block 64. y==8 (x<8): combine start/end partials.
// ---------------------------------------------------------------------------
__global__ __launch_bounds__(64, 4) void bigram_kernel(
    const ushort_t* __restrict__ leftH, const ushort_t* __restrict__ rightH,
    const float* __restrict__ Wo,   const float* __restrict__ bo,
    const float* __restrict__ parts,
    const float* __restrict__ bs2,  const float* __restrict__ be2,
    float* __restrict__ out, float* __restrict__ start_out,
    float* __restrict__ end_out)
{
    const int x = blockIdx.x, y = blockIdx.y, b = blockIdx.z;
    const int t = threadIdx.x;

    if (y == 8) {
        if (x < 8) {
            const int r = (b * 8 + x) * 64 + t;
            start_out[r] = parts[r] + parts[ROWS + r] + bs2[0];
            end_out[r]   = parts[2 * ROWS + r] + parts[3 * ROWS + r] + be2[0];
        }
        return;
    }

    const int j  = y * 64 + t;
    const int i0 = x * 4;

    const ushort_t* lrow  = leftH  + ((size_t)b * Nc + j) * Pc;    // per-lane
    const ushort_t* rbase = rightH + ((size_t)b * Nc + i0) * Pc;   // uniform

    float acc0[4] = {}, acc1[4] = {};
    const h2v hz = {(_Float16)0.f, (_Float16)0.f};

    #pragma unroll
    for (int half = 0; half < 2; ++half) {
        const int hoff = half * 64;   // ushort offset

        unsigned lreg[32];
        #pragma unroll
        for (int c = 0; c < 8; ++c) {
            u32x4 v = *(const u32x4*)(lrow + hoff + c * 8);
            lreg[4 * c]     = v[0]; lreg[4 * c + 1] = v[1];
            lreg[4 * c + 2] = v[2]; lreg[4 * c + 3] = v[3];
        }
        unsigned wreg[32];
        #pragma unroll
        for (int m = 0; m < 32; ++m)
            wreg[m] = packh2(Wo[hoff + 2 * m], Wo[hoff + 2 * m + 1]);

        #pragma unroll
        for (int i = 0; i < 4; ++i) {
            unsigned rreg[32];
            #pragma unroll
            for (int c = 0; c < 8; ++c) {
                u32x4 v = *(const u32x4*)(rbase + (size_t)i * Pc + hoff + c * 8);
                rreg[4 * c]     = v[0]; rreg[4 * c + 1] = v[1];
                rreg[4 * c + 2] = v[2]; rreg[4 * c + 3] = v[3];
            }
            float a0 = acc0[i], a1 = acc1[i];
            #pragma unroll
            for (int m = 0; m < 32; m += 2) {
                h2v s0 = __builtin_bit_cast(h2v, lreg[m])
                       + __builtin_bit_cast(h2v, rreg[m]);
                s0 = __builtin_elementwise_max(s0, hz);
                a0 = __builtin_amdgcn_fdot2(
                         s0, __builtin_bit_cast(h2v, wreg[m]), a0, false);
                h2v s1 = __builtin_bit_cast(h2v, lreg[m + 1])
                       + __builtin_bit_cast(h2v, rreg[m + 1]);
                s1 = __builtin_elementwise_max(s1, hz);
                a1 = __builtin_amdgcn_fdot2(
                         s1, __builtin_bit_cast(h2v, wreg[m + 1]), a1, false);
            }
            acc0[i] = a0; acc1[i] = a1;
        }
    }

    const float bias = bo[0];
    #pragma unroll
    for (int i = 0; i < 4; ++i)
        out[((size_t)b * Nc + i0 + i) * Nc + j] = acc0[i] + acc1[i] + bias;
}

extern "C" void kernel_launch(void* const* d_in, const int* in_sizes, int n_in,
                              void* d_out, int out_size, void* d_ws, size_t ws_size,
                              hipStream_t stream) {
    const float* input = (const float*)d_in[0];
    const float* Wl  = (const float*)d_in[1];
    const float* bl  = (const float*)d_in[2];
    const float* Wr  = (const float*)d_in[3];
    const float* Wo  = (const float*)d_in[4];
    const float* bo  = (const float*)d_in[5];
    const float* Ws1 = (const float*)d_in[6];
    const float* bs1 = (const float*)d_in[7];
    const float* Ws2 = (const float*)d_in[8];
    const float* bs2 = (const float*)d_in[9];
    const float* We1 = (const float*)d_in[10];
    const float* be1 = (const float*)d_in[11];
    const float* We2 = (const float*)d_in[12];
    const float* be2 = (const float*)d_in[13];

    float* out    = (float*)d_out;
    float* bigram = out;
    float* start  = out + (size_t)Bc * Nc * Nc;
    float* end    = start + (size_t)Bc * Nc;

    ushort_t* leftH  = (ushort_t*)d_ws;                        // 2048*128 f16
    ushort_t* rightH = leftH + (size_t)ROWS * Pc;              // 2048*128 f16
    float* parts     = (float*)(rightH + (size_t)ROWS * Pc);   // 4*2048 f32

    mfma_proj5<<<dim3(64, 8), 256, 0, stream>>>(
        input, Wl, bl, Wr, Ws1, bs1, Ws2, We1, be1, We2,
        leftH, rightH, parts);

    bigram_kernel<<<dim3(128, 9, 4), 64, 0, stream>>>(
        leftH, rightH, Wo, bo, parts, bs2, be2, bigram, start, end);
}

// Round 15
// 31.546 us; speedup vs baseline: 1.1084x; 1.1084x over previous
//
#include <hip/hip_runtime.h>

typedef unsigned short ushort_t;
using f32x4  = __attribute__((ext_vector_type(4))) float;
using bf16x8 = __attribute__((ext_vector_type(8))) short;
using u16x8  = __attribute__((ext_vector_type(8))) unsigned short;
using h2v    = __attribute__((ext_vector_type(2))) _Float16;
using u32x4  = __attribute__((ext_vector_type(4))) unsigned;

constexpr int Bc = 4;
constexpr int Nc = 512;
constexpr int Dc = 512;
constexpr int Pc = 128;
constexpr int ROWS = Bc * Nc;   // 2048

__device__ inline unsigned short f2bf(float f) {
    unsigned u = __builtin_bit_cast(unsigned, f);
    unsigned r = u + 0x7fffu + ((u >> 16) & 1u);   // RNE
    return (unsigned short)(r >> 16);
}

__device__ inline void gload_lds16(const void* g, void* l) {
    __builtin_amdgcn_global_load_lds(
        (const __attribute__((address_space(1))) unsigned int*)g,
        (__attribute__((address_space(3))) unsigned int*)l, 16, 0, 0);
}

__device__ inline unsigned packh2(float a, float b) {
    unsigned short lo = __builtin_bit_cast(unsigned short, (_Float16)a);
    unsigned short hi = __builtin_bit_cast(unsigned short, (_Float16)b);
    return (unsigned)lo | ((unsigned)hi << 16);
}

// ---------------------------------------------------------------------------
// K0: W-only convert -> WcatT2[nt(8)][ks(8)][kc(8)][col(64)][8] bf16.
// Each W strip converted exactly once (fusing this into proj duplicates it
// 64x — measured +4us regression in round 14).
// ---------------------------------------------------------------------------
__global__ __launch_bounds__(256) void wconv_kernel(
    const float* __restrict__ Wl,  const float* __restrict__ Wr,
    const float* __restrict__ Ws1, const float* __restrict__ We1,
    ushort_t* __restrict__ WcatT2)
{
    const int bx = blockIdx.x, t = threadIdx.x;
    __shared__ float T[64][68];

    const int nt = bx >> 3, ks = bx & 7;
    const int mi = nt >> 1, cm0 = (nt & 1) * 64;
    const float* Wm = (mi == 0) ? Wl : (mi == 1) ? Wr : (mi == 2) ? Ws1 : We1;

    const int kk_ = t >> 4, cc = (t & 15) << 2;
    #pragma unroll
    for (int u = 0; u < 4; ++u)
        *(float4*)&T[kk_ + 16 * u][cc] =
            *(const float4*)&Wm[(size_t)(ks * 64 + kk_ + 16 * u) * Pc + cm0 + cc];
    __syncthreads();

    const int col = t & 63, c2 = t >> 6;
    #pragma unroll
    for (int h = 0; h < 2; ++h) {
        const int kc = c2 + h * 4;
        u16x8 o;
        #pragma unroll
        for (int i = 0; i < 8; ++i) o[i] = f2bf(T[kc * 8 + i][col]);
        *(u16x8*)(WcatT2 + ((size_t)(nt * 8 + ks) * 8 + kc) * 512 + col * 8) = o;
    }
}

// ---------------------------------------------------------------------------
// K1: proj GEMM with fused input conversion (round-8 structure).
// grid (64 mt2, 8 ny) = 512 blocks -> 2 blocks/CU.
// ---------------------------------------------------------------------------
__global__ __launch_bounds__(256) void mfma_proj4(
    const float* __restrict__ input, const ushort_t* __restrict__ WcatT2,
    const float* __restrict__ bl,
    const float* __restrict__ bs1, const float* __restrict__ Ws2,
    const float* __restrict__ be1, const float* __restrict__ We2,
    ushort_t* __restrict__ leftH, ushort_t* __restrict__ rightH,
    float* __restrict__ parts)
{
    const int mt2 = blockIdx.x, ny = blockIdx.y;
    const int row0 = mt2 * 32;
    const int t = threadIdx.x, w = t >> 6, l = t & 63;
    const int wm = w & 1, wn = w >> 1;
    const int fr = l & 15, fg = l >> 4;

    __shared__ ushort_t As[2][2048];
    __shared__ ushort_t Bs[2][4096];
    __shared__ float red[64];

    const ushort_t* Bbase = WcatT2 + (size_t)ny * 8 * 4096;

    const int sr = t >> 3, skc = t & 7;
    const float* Ain = input + (size_t)(row0 + sr) * Dc + skc * 8;
    ushort_t* Ad0 = &As[0][skc * 256 + sr * 8];
    ushort_t* Ad1 = &As[1][skc * 256 + sr * 8];

    f32x4 acc0 = {0.f, 0.f, 0.f, 0.f}, acc1 = {0.f, 0.f, 0.f, 0.f};
    float4 aE0, aE1, aO0, aO1;

#define ALOAD(P0, P1, KS)                                     \
    {                                                         \
        const float* s_ = Ain + (KS) * 64;                    \
        P0 = *(const float4*)s_;                              \
        P1 = *(const float4*)(s_ + 4);                        \
    }

#define AWRITE(DST, P0, P1)                                   \
    {                                                         \
        u16x8 o_;                                             \
        o_[0] = f2bf(P0.x); o_[1] = f2bf(P0.y);               \
        o_[2] = f2bf(P0.z); o_[3] = f2bf(P0.w);               \
        o_[4] = f2bf(P1.x); o_[5] = f2bf(P1.y);               \
        o_[6] = f2bf(P1.z); o_[7] = f2bf(P1.w);               \
        *(u16x8*)(DST) = o_;                                  \
    }

#define BSTAGE(BI, KS)                                                   \
    {                                                                    \
        const ushort_t* gb = Bbase + (KS) * 4096;                        \
        gload_lds16(gb + w * 512 + l * 8, &Bs[BI][w * 512]);             \
        gload_lds16(gb + (w + 4) * 512 + l * 8, &Bs[BI][(w + 4) * 512]); \
    }

#define COMPUTE(BI)                                                           \
    {                                                                         \
        _Pragma("unroll") for (int kk = 0; kk < 2; ++kk) {                    \
            const int kc = kk * 4 + fg;                                       \
            bf16x8 a  = *(const bf16x8*)&As[BI][kc * 256 + (wm * 16 + fr) * 8];       \
            bf16x8 b0 = *(const bf16x8*)&Bs[BI][kc * 512 + (wn * 32 + fr) * 8];       \
            bf16x8 b1 = *(const bf16x8*)&Bs[BI][kc * 512 + (wn * 32 + 16 + fr) * 8];  \
            acc0 = __builtin_amdgcn_mfma_f32_16x16x32_bf16(a, b0, acc0, 0, 0, 0);     \
            acc1 = __builtin_amdgcn_mfma_f32_16x16x32_bf16(a, b1, acc1, 0, 0, 0);     \
        }                                                                     \
    }

    ALOAD(aE0, aE1, 0);
    BSTAGE(0, 0);
    AWRITE(Ad0, aE0, aE1);
    ALOAD(aO0, aO1, 1);
    __syncthreads();

    #pragma unroll
    for (int ks2 = 0; ks2 < 8; ks2 += 2) {
        BSTAGE(1, ks2 + 1);
        if (ks2 + 2 < 8) ALOAD(aE0, aE1, ks2 + 2);
        COMPUTE(0);
        AWRITE(Ad1, aO0, aO1);
        __syncthreads();
        if (ks2 + 2 < 8) {
            BSTAGE(0, ks2 + 2);
            if (ks2 + 3 < 8) ALOAD(aO0, aO1, ks2 + 3);
        }
        COMPUTE(1);
        if (ks2 + 2 < 8) AWRITE(Ad0, aE0, aE1);
        __syncthreads();
    }
#undef ALOAD
#undef AWRITE
#undef BSTAGE
#undef COMPUTE

    const int fq4 = fg << 2;
    if (ny < 4) {
        ushort_t* outp = (ny < 2) ? leftH : rightH;
        const int cb = (ny & 1) * 64 + wn * 32;
        #pragma unroll
        for (int n = 0; n < 2; ++n) {
            const int col = cb + n * 16 + fr;
            const float bv = (ny < 2) ? bl[col] : 0.f;
            const f32x4 av = n ? acc1 : acc0;
            #pragma unroll
            for (int q = 0; q < 4; ++q) {
                float v = av[q] + bv;
                outp[(size_t)(row0 + wm * 16 + fq4 + q) * Pc + col] =
                    __builtin_bit_cast(ushort_t, (_Float16)v);
            }
        }
    } else {
        const int pi = ny - 4;
        const float* b1 = (ny < 6) ? bs1 : be1;
        const float* W2 = (ny < 6) ? Ws2 : We2;
        const int pb = (pi & 1) * 64;
        #pragma unroll
        for (int q = 0; q < 4; ++q) {
            const int cp0 = pb + wn * 32 + fr;
            const int cp1 = pb + wn * 32 + 16 + fr;
            float v = fmaxf(acc0[q] + b1[cp0], 0.f) * W2[cp0]
                    + fmaxf(acc1[q] + b1[cp1], 0.f) * W2[cp1];
            v += __shfl_xor(v, 1);
            v += __shfl_xor(v, 2);
            v += __shfl_xor(v, 4);
            v += __shfl_xor(v, 8);
            if (fr == 0) red[wn * 32 + wm * 16 + fq4 + q] = v;
        }
        __syncthreads();
        if (t < 32) parts[pi * ROWS + row0 + t] = red[t] + red[32 + t];
    }
}

// ---------------------------------------------------------------------------
// K2: bigram v9 — no-LDS, no-barrier, 1-wave blocks for latency tolerance.
// grid (128, 9, 4), block 64. y==8 (x<8): combine start/end partials.
// ---------------------------------------------------------------------------
__global__ __launch_bounds__(64, 4) void bigram_kernel(
    const ushort_t* __restrict__ leftH, const ushort_t* __restrict__ rightH,
    const float* __restrict__ Wo,   const float* __restrict__ bo,
    const float* __restrict__ parts,
    const float* __restrict__ bs2,  const float* __restrict__ be2,
    float* __restrict__ out, float* __restrict__ start_out,
    float* __restrict__ end_out)
{
    const int x = blockIdx.x, y = blockIdx.y, b = blockIdx.z;
    const int t = threadIdx.x;

    if (y == 8) {
        if (x < 8) {
            const int r = (b * 8 + x) * 64 + t;
            start_out[r] = parts[r] + parts[ROWS + r] + bs2[0];
            end_out[r]   = parts[2 * ROWS + r] + parts[3 * ROWS + r] + be2[0];
        }
        return;
    }

    const int j  = y * 64 + t;
    const int i0 = x * 4;

    const ushort_t* lrow  = leftH  + ((size_t)b * Nc + j) * Pc;    // per-lane
    const ushort_t* rbase = rightH + ((size_t)b * Nc + i0) * Pc;   // uniform

    float acc0[4] = {}, acc1[4] = {};
    const h2v hz = {(_Float16)0.f, (_Float16)0.f};

    #pragma unroll
    for (int half = 0; half < 2; ++half) {
        const int hoff = half * 64;   // ushort offset

        unsigned lreg[32];
        #pragma unroll
        for (int c = 0; c < 8; ++c) {
            u32x4 v = *(const u32x4*)(lrow + hoff + c * 8);
            lreg[4 * c]     = v[0]; lreg[4 * c + 1] = v[1];
            lreg[4 * c + 2] = v[2]; lreg[4 * c + 3] = v[3];
        }
        unsigned wreg[32];
        #pragma unroll
        for (int m = 0; m < 32; ++m)
            wreg[m] = packh2(Wo[hoff + 2 * m], Wo[hoff + 2 * m + 1]);

        #pragma unroll
        for (int i = 0; i < 4; ++i) {
            unsigned rreg[32];
            #pragma unroll
            for (int c = 0; c < 8; ++c) {
                u32x4 v = *(const u32x4*)(rbase + (size_t)i * Pc + hoff + c * 8);
                rreg[4 * c]     = v[0]; rreg[4 * c + 1] = v[1];
                rreg[4 * c + 2] = v[2]; rreg[4 * c + 3] = v[3];
            }
            float a0 = acc0[i], a1 = acc1[i];
            #pragma unroll
            for (int m = 0; m < 32; m += 2) {
                h2v s0 = __builtin_bit_cast(h2v, lreg[m])
                       + __builtin_bit_cast(h2v, rreg[m]);
                s0 = __builtin_elementwise_max(s0, hz);
                a0 = __builtin_amdgcn_fdot2(
                         s0, __builtin_bit_cast(h2v, wreg[m]), a0, false);
                h2v s1 = __builtin_bit_cast(h2v, lreg[m + 1])
                       + __builtin_bit_cast(h2v, rreg[m + 1]);
                s1 = __builtin_elementwise_max(s1, hz);
                a1 = __builtin_amdgcn_fdot2(
                         s1, __builtin_bit_cast(h2v, wreg[m + 1]), a1, false);
            }
            acc0[i] = a0; acc1[i] = a1;
        }
    }

    const float bias = bo[0];
    #pragma unroll
    for (int i = 0; i < 4; ++i)
        out[((size_t)b * Nc + i0 + i) * Nc + j] = acc0[i] + acc1[i] + bias;
}

extern "C" void kernel_launch(void* const* d_in, const int* in_sizes, int n_in,
                              void* d_out, int out_size, void* d_ws, size_t ws_size,
                              hipStream_t stream) {
    const float* input = (const float*)d_in[0];
    const float* Wl  = (const float*)d_in[1];
    const float* bl  = (const float*)d_in[2];
    const float* Wr  = (const float*)d_in[3];
    const float* Wo  = (const float*)d_in[4];
    const float* bo  = (const float*)d_in[5];
    const float* Ws1 = (const float*)d_in[6];
    const float* bs1 = (const float*)d_in[7];
    const float* Ws2 = (const float*)d_in[8];
    const float* bs2 = (const float*)d_in[9];
    const float* We1 = (const float*)d_in[10];
    const float* be1 = (const float*)d_in[11];
    const float* We2 = (const float*)d_in[12];
    const float* be2 = (const float*)d_in[13];

    float* out    = (float*)d_out;
    float* bigram = out;
    float* start  = out + (size_t)Bc * Nc * Nc;
    float* end    = start + (size_t)Bc * Nc;

    ushort_t* leftH  = (ushort_t*)d_ws;                        // 2048*128 f16
    ushort_t* rightH = leftH + (size_t)ROWS * Pc;              // 2048*128 f16
    float* parts     = (float*)(rightH + (size_t)ROWS * Pc);   // 4*2048 f32
    ushort_t* WcatT2 = (ushort_t*)(parts + 4 * ROWS);          // 512*512 bf16

    wconv_kernel<<<64, 256, 0, stream>>>(Wl, Wr, Ws1, We1, WcatT2);

    mfma_proj4<<<dim3(64, 8), 256, 0, stream>>>(
        input, WcatT2, bl, bs1, Ws2, be1, We2, leftH, rightH, parts);

    bigram_kernel<<<dim3(128, 9, 4), 64, 0, stream>>>(
        leftH, rightH, Wo, bo, parts, bs2, be2, bigram, start, end);
}